// Round 6
// baseline (241.505 us; speedup 1.0000x reference)
//
#include <hip/hip_runtime.h>
#include <stdint.h>

// Problem constants (fixed by reference setup_inputs): B=32, C=1, H=384, W=1280
#define NB 32
#define NPIX 491520            // 1*384*1280
#define NT 256

// K1 geometry — empirically best across rounds 0-5:
//   8192 px/block (1920 blocks, 7.5/CU, ~30 waves/CU) beat 4096 px/block by
//   38% (43.2 vs 59.5 us) at identical FETCH_SIZE: per-block epilogue cost +
//   per-block MLP dominate over any refill/balance effect.
#define K1CHUNKS 60
#define K1CHUNK 8192           // px per block
#define K1HALF4 (K1CHUNK / 8)  // 1024 float4 per half = 4*NT (compile-time 4-trip)
#define K1IT 4                 // K1HALF4 / NT
#define K1GROUPS (K1CHUNK / 4) // 2048 4-px groups per block
#define K1WORDS (K1CHUNK / 64) // 128 u64 bitmap words per block

// K2 geometry — round-0 operating point
#define K2CHUNKS 32
#define K2CHUNK 15360           // px per block
#define K2IT (K2CHUNK / 4 / NT) // 15 float4 iters per thread
#define K2WORDS (K2CHUNK / 64)  // 240 u64 bitmap words per block

#define NBINS 4096             // 8-bit exp + 4-bit mantissa key (monotone in r >= 0)

// hist64 packing: bits [63:40] = count, bits [39:0] = sum of low-19 mantissa bits.
// Per sample: cnt <= 491520 < 2^24; sum(low19) < 491520 * 2^19 ~ 2^38 < 2^40. Exact.
#define CNT1 (1ull << 40)
#define SLOWMASK ((1ull << 40) - 1ull)

// native vector types for __builtin_nontemporal_load (HIP_vector_type is rejected)
typedef float  vf4 __attribute__((ext_vector_type(4)));
typedef int    vi4 __attribute__((ext_vector_type(4)));

struct Ws {
  double moments[NB][5];                 // n, sum_p, sum_g, sum_pp, sum_pg (memset-zeroed)
  double loss_sum;                       // fused k_fin epilogue accumulator (memset-zeroed)
  unsigned long long done;               // fused k_fin done-counter (memset-zeroed)
  unsigned long long hist64[NB][NBINS];  // zeroed by k_mom threads (next-launch consumer)
};

__device__ __forceinline__ double wave_sum_d(double v) {
#pragma unroll
  for (int o = 32; o > 0; o >>= 1) v += __shfl_down(v, o, 64);
  return v;
}

__device__ __forceinline__ double block_sum_d(double v, double* red4) {
  v = wave_sum_d(v);
  const int lane = threadIdx.x & 63, w = threadIdx.x >> 6;
  if (lane == 0) red4[w] = v;
  __syncthreads();
  return red4[0] + red4[1] + red4[2] + red4[3];
}

__device__ __forceinline__ int k_from_n(double n) {
  return (int)floorf(0.8f * (float)n);   // matches jnp.floor((1-0.2)*n) in f32
}

__device__ __forceinline__ void coef_from_moments(const Ws* ws, int b, float* a_out, float* be_out) {
  const double n = ws->moments[b][0];
  const double ns = n > 1.0 ? n : 1.0;
  const double md = ws->moments[b][1] / ns;
  const double mz = ws->moments[b][2] / ns;
  const double var = ws->moments[b][3] / ns - md * md;
  const double cov = ws->moments[b][4] / ns - md * mz;
  const double a = cov / (var + 1e-6);
  *a_out = (float)a;
  *be_out = (float)(mz - a * md);
}

// exact sum of all residuals in `bin` given its packed (cnt, sum_low19)
__device__ __forceinline__ double bin_sum(int bin, unsigned long long h) {
  const double cnt = (double)(h >> 40);
  const double slow = (double)(h & SLOWMASK);
  const int e = bin >> 4, t4 = bin & 15;
  if (e == 0)  // subnormal: r = mant23 * 2^-149
    return ldexp(cnt * (double)(t4 << 19) + slow, -149);
  // r = 2^(e-127) * (1 + mant23*2^-23), mant23 = (t4<<19) + low19
  return ldexp(cnt * (1.0 + (double)t4 * 0.0625) + slow * (1.0 / 8388608.0), e - 127);
}

// ---------------- K1: moments + mask bitmap + zero hist region ----------------
// Round-6: compile-time 4-trip loop + 2-deep p/g prefetch (the round-5 k_hist
// trick). Mask stays in-order to keep VGPR <= 64 for the 8-waves/EU bound.
template <bool BM>
__global__ __launch_bounds__(NT, 8) void k_mom(
    const float* __restrict__ pred, const float* __restrict__ gt,
    const int* __restrict__ mask, Ws* __restrict__ ws,
    unsigned long long* __restrict__ bm) {
  const int b = blockIdx.y;
  const size_t base = (size_t)b * NPIX + (size_t)blockIdx.x * K1CHUNK;
  const vf4* p4 = (const vf4*)(pred + base);
  const vf4* g4 = (const vf4*)(gt + base);
  const vi4* m4 = (const vi4*)(mask + base);
  __shared__ unsigned char nib[K1GROUPS];   // 2 KB: 4-px mask nibble per group
  __shared__ double red[4][5];
  float n = 0.f, sp = 0.f, sg = 0.f, spp = 0.f, spg = 0.f;
  const int t = (int)threadIdx.x;
  // read-exactly-once streams: non-temporal -> no L2/L3 allocation, no
  // eviction of harness-restored warm lines. Round-1 A/B: plain loads were
  // 1.7x slower at identical FETCH_SIZE (L2-allocate path pure overhead).
  vf4 pa = __builtin_nontemporal_load(&p4[t]);
  vf4 pb = __builtin_nontemporal_load(&p4[t + K1HALF4]);
  vf4 ga = __builtin_nontemporal_load(&g4[t]);
  vf4 gb = __builtin_nontemporal_load(&g4[t + K1HALF4]);
#pragma unroll
  for (int j = 0; j < K1IT; j++) {
    const int i = j * NT + t;
    vf4 pa2, pb2, ga2, gb2;
    if (j + 1 < K1IT) {   // prefetch next iteration's p/g before consuming
      pa2 = __builtin_nontemporal_load(&p4[i + NT]);
      pb2 = __builtin_nontemporal_load(&p4[i + NT + K1HALF4]);
      ga2 = __builtin_nontemporal_load(&g4[i + NT]);
      gb2 = __builtin_nontemporal_load(&g4[i + NT + K1HALF4]);
    }
    vi4 ma = __builtin_nontemporal_load(&m4[i]);
    vi4 mb = __builtin_nontemporal_load(&m4[i + K1HALF4]);
    const float pe[8] = {pa.x, pa.y, pa.z, pa.w, pb.x, pb.y, pb.z, pb.w};
    const float ge[8] = {ga.x, ga.y, ga.z, ga.w, gb.x, gb.y, gb.z, gb.w};
    const int   me[8] = {ma.x, ma.y, ma.z, ma.w, mb.x, mb.y, mb.z, mb.w};
#pragma unroll
    for (int jj = 0; jj < 8; jj++) {
      const float mf = me[jj] ? 1.f : 0.f;
      const float pm = pe[jj] * mf;
      const float gm = ge[jj] * mf;
      n += mf; sp += pm; sg += gm;
      spp = fmaf(pe[jj], pm, spp);
      spg = fmaf(pe[jj], gm, spg);
    }
    if (BM) {
      nib[i] = (unsigned char)((me[0] ? 1 : 0) | (me[1] ? 2 : 0) |
                               (me[2] ? 4 : 0) | (me[3] ? 8 : 0));
      nib[i + K1HALF4] = (unsigned char)((me[4] ? 1 : 0) | (me[5] ? 2 : 0) |
                                         (me[6] ? 4 : 0) | (me[7] ? 8 : 0));
    }
    pa = pa2; pb = pb2; ga = ga2; gb = gb2;
  }
  if (BM) {
    __syncthreads();
    if (t < K1WORDS) {   // assemble 16 nibbles -> one u64 bitmap word
      unsigned long long w = 0;
#pragma unroll
      for (int j = 0; j < 16; j++)
        w |= (unsigned long long)nib[t * 16 + j] << (4 * j);
      bm[base / 64 + t] = w;
    }
    // no second sync needed: nib is never touched again; epilogue uses red[][]
  }
  // merged epilogue: 5 wave reductions -> one LDS pass -> ONE sync -> 5
  // parallel atomics (round-3 win: k_mom 43.2 -> <40 us)
  double v[5] = {(double)n, (double)sp, (double)sg, (double)spp, (double)spg};
#pragma unroll
  for (int q = 0; q < 5; q++) v[q] = wave_sum_d(v[q]);
  const int lane = t & 63, w = t >> 6;
  if (lane == 0) {
#pragma unroll
    for (int q = 0; q < 5; q++) red[w][q] = v[q];
  }
  __syncthreads();
  if (t < 5) {
    atomicAdd(&ws->moments[b][t], red[0][t] + red[1][t] + red[2][t] + red[3][t]);
  }
  // zero hist64 for k_hist (consumed next launch): one u64 per early thread
  const int flat = (b * K1CHUNKS + (int)blockIdx.x) * NT + t;
  if (flat < NB * NBINS) ((unsigned long long*)ws->hist64)[flat] = 0ull;
}

// ---------------- K2: 4096-bin packed (cnt,sum_low19) histogram, f32 inputs ----------------
// Round-4 lesson: do NOT add post-flush __syncthreads/__threadfence here — the
// end-of-kernel implicit drain is free, explicit drain cost +28 us/dispatch.
// Round-6: 3-deep p/g pipeline (round-5's 2-deep gained 1.4 us; per-iter compute
// covers only a fraction of ~900-cyc HBM latency, so one more stage should pay).
template <bool BM>
__global__ __launch_bounds__(NT, 4) void k_hist(
    const float* __restrict__ pred, const float* __restrict__ gt,
    const int* __restrict__ mask, const unsigned long long* __restrict__ bm,
    Ws* __restrict__ ws) {
  __shared__ unsigned long long h64[NBINS];   // 32 KB
  __shared__ unsigned long long smask[K2WORDS];
  for (int i = threadIdx.x; i < NBINS; i += NT) h64[i] = 0ull;
  const int b = blockIdx.y;
  const int tid = (int)threadIdx.x;
  const size_t base = (size_t)b * NPIX + (size_t)blockIdx.x * K2CHUNK;
  if (BM) {
    if (tid < K2WORDS) smask[tid] = bm[base / 64 + tid];
  }
  float a, be;
  coef_from_moments(ws, b, &a, &be);
  __syncthreads();
  const vf4* p4 = (const vf4*)(pred + base);
  const vf4* g4 = (const vf4*)(gt + base);
  const vi4* m4 = (const vi4*)(mask + base);
  vf4 p0 = __builtin_nontemporal_load(&p4[tid]);
  vf4 g0 = __builtin_nontemporal_load(&g4[tid]);
  vf4 p1 = __builtin_nontemporal_load(&p4[tid + NT]);
  vf4 g1 = __builtin_nontemporal_load(&g4[tid + NT]);
  vi4 m0, m1;
  if (!BM) {
    m0 = __builtin_nontemporal_load(&m4[tid]);
    m1 = __builtin_nontemporal_load(&m4[tid + NT]);
  }
  for (int j = 0; j < K2IT; j++) {
    const int i = j * NT + tid;
    vf4 p2, g2;
    vi4 m2;
    if (j + 2 < K2IT) {   // prefetch two iterations ahead
      p2 = __builtin_nontemporal_load(&p4[i + 2 * NT]);
      g2 = __builtin_nontemporal_load(&g4[i + 2 * NT]);
      if (!BM) m2 = __builtin_nontemporal_load(&m4[i + 2 * NT]);
    }
    const float pe[4] = {p0.x, p0.y, p0.z, p0.w};
    const float ge[4] = {g0.x, g0.y, g0.z, g0.w};
    int me[4];
    if (BM) {
      const unsigned int nb4 =
          (unsigned int)(smask[i >> 4] >> ((i & 15) * 4)) & 0xFu;
      me[0] = nb4 & 1; me[1] = nb4 & 2; me[2] = nb4 & 4; me[3] = nb4 & 8;
    } else {
      me[0] = m0.x; me[1] = m0.y; me[2] = m0.z; me[3] = m0.w;
    }
#pragma unroll
    for (int l = 0; l < 4; l++) {
      if (!me[l]) continue;
      const float r = fabsf(fmaf(a, pe[l], be) - ge[l]);
      const uint32_t t = __float_as_uint(r);
      atomicAdd(&h64[t >> 19], CNT1 | (unsigned long long)(t & 0x7FFFFu));
    }
    p0 = p1; g0 = g1; p1 = p2; g1 = g2;
    if (!BM) { m0 = m1; m1 = m2; }
  }
  __syncthreads();
  // flush nonzero bins; consumed by k_fin in the NEXT launch (no fences needed);
  // waves retire with flush atomics in flight (implicit end-of-kernel drain).
  for (int i = tid; i < NBINS; i += NT) {
    const unsigned long long v = h64[i];
    if (v) atomicAdd(&ws->hist64[b][i], v);
  }
}

// ---------------- K3: per-sample trimmed mean + fused cross-sample average ----------------
__global__ __launch_bounds__(NT) void k_fin(Ws* __restrict__ ws, float* __restrict__ out) {
  const int b = (int)blockIdx.x;
  const int tid = (int)threadIdx.x;
  __shared__ int pc[NT];
  __shared__ int shX, shCum;
  __shared__ double red4[4];
  const unsigned long long* H = ws->hist64[b];
  unsigned long long h[16];
  int lc = 0;
#pragma unroll
  for (int j = 0; j < 16; j++) { h[j] = H[tid * 16 + j]; lc += (int)(h[j] >> 40); }
  pc[tid] = lc;
  if (tid == 0) { shX = NBINS; shCum = 0; }
  __syncthreads();
  int pre = 0;
  for (int t = 0; t < tid; t++) pre += pc[t];   // LDS broadcast reads
  const int k = k_from_n(ws->moments[b][0]);
  if (k > 0 && pre < k && pre + lc >= k) {      // exactly one thread
    int cum = pre;
#pragma unroll
    for (int j = 0; j < 16; j++) {
      const int c = (int)(h[j] >> 40);
      if (cum + c >= k) { shX = tid * 16 + j; shCum = cum; break; }
      cum += c;
    }
  }
  __syncthreads();
  const int X = shX;
  double below = 0.0;
#pragma unroll
  for (int j = 0; j < 16; j++) {
    const int idx = tid * 16 + j;
    if (idx < X) below += bin_sum(idx, h[j]);
  }
  const double tot = block_sum_d(below, red4);
  if (tid == 0) {
    double loss = 0.0;
    if (k > 0 && X < NBINS) {
      const unsigned long long hX = H[X];
      const double cX = (double)(hX >> 40);
      // crossing-bin partial at the bin's exact mean (bin rel. width 2^-4)
      const double partial = (double)(k - shCum) * (bin_sum(X, hX) / cX);
      loss = (tot + partial) / (double)k;
    }
    // fused k_out: device-scope accumulate; last block writes the mean.
    atomicAdd(&ws->loss_sum, loss);
    __threadfence();
    const unsigned long long old = atomicAdd(&ws->done, 1ull);
    if (old == (unsigned long long)(NB - 1)) {
      __threadfence();
      const double sum = atomicAdd(&ws->loss_sum, 0.0);  // coherent read at L2
      out[0] = (float)(sum / (double)NB);
    }
  }
}

extern "C" void kernel_launch(void* const* d_in, const int* in_sizes, int n_in,
                              void* d_out, int out_size, void* d_ws, size_t ws_size,
                              hipStream_t stream) {
  const float* pred = (const float*)d_in[0];
  const float* gt   = (const float*)d_in[1];
  const int*   mask = (const int*)d_in[2];
  float* out = (float*)d_out;
  Ws* ws = (Ws*)d_ws;

  const size_t boff = (sizeof(Ws) + 255) & ~(size_t)255;
  const size_t bbytes = (size_t)NB * NPIX / 8;                  // 2 MB mask bitmap
  const bool bm_ok = ws_size >= boff + bbytes;                  // environment-constant
  unsigned long long* bm = (unsigned long long*)((char*)d_ws + boff);

  // zero moments + loss_sum + done; hist64 is zeroed by k_mom's threads
  (void)hipMemsetAsync(d_ws, 0, sizeof(double) * NB * 5 + 16, stream);

  dim3 g1(K1CHUNKS, NB);
  dim3 g2(K2CHUNKS, NB);
  if (bm_ok) {
    k_mom<true><<<g1, NT, 0, stream>>>(pred, gt, mask, ws, bm);
    k_hist<true><<<g2, NT, 0, stream>>>(pred, gt, mask, bm, ws);
  } else {
    k_mom<false><<<g1, NT, 0, stream>>>(pred, gt, mask, ws, nullptr);
    k_hist<false><<<g2, NT, 0, stream>>>(pred, gt, mask, nullptr, ws);
  }
  k_fin<<<NB, NT, 0, stream>>>(ws, out);
}

// Round 7
// 203.178 us; speedup vs baseline: 1.1886x; 1.1886x over previous
//
#include <hip/hip_runtime.h>
#include <stdint.h>

// Problem constants (fixed by reference setup_inputs): B=32, C=1, H=384, W=1280
#define NB 32
#define NPIX 491520            // 1*384*1280
#define NT 256

// K1 geometry — empirically best across rounds 0-6:
//   8192 px/block (1920 blocks, 7.5/CU, ~30 waves/CU) beat 4096 px/block by
//   38% (43.2 vs 59.5 us) at identical FETCH_SIZE: per-block epilogue cost +
//   per-block MLP dominate over any refill/balance effect.
// Round-6 lesson: do NOT software-pipeline this kernel. __launch_bounds__(NT,8)
// caps VGPR at 64/wave; 2-deep p/g prefetch overflowed the cap -> scratch spill
// (WRITE_SIZE 3.5->87.5 MB, dur 39->75 us). Latency hiding here comes from TLP
// (30 waves/CU), not ILP. Keep the simple strided loop at 28-32 VGPRs.
#define K1CHUNKS 60
#define K1CHUNK 8192           // px per block
#define K1HALF4 (K1CHUNK / 8)  // 1024 float4 per half, 2-way unrolled strided
#define K1GROUPS (K1CHUNK / 4) // 2048 4-px groups per block
#define K1WORDS (K1CHUNK / 64) // 128 u64 bitmap words per block

// K2 geometry — round-0 operating point
#define K2CHUNKS 32
#define K2CHUNK 15360           // px per block
#define K2IT (K2CHUNK / 4 / NT) // 15 float4 iters per thread
#define K2WORDS (K2CHUNK / 64)  // 240 u64 bitmap words per block

#define NBINS 4096             // 8-bit exp + 4-bit mantissa key (monotone in r >= 0)

// hist64 packing: bits [63:40] = count, bits [39:0] = sum of low-19 mantissa bits.
// Per sample: cnt <= 491520 < 2^24; sum(low19) < 491520 * 2^19 ~ 2^38 < 2^40. Exact.
#define CNT1 (1ull << 40)
#define SLOWMASK ((1ull << 40) - 1ull)

// native vector types for __builtin_nontemporal_load (HIP_vector_type is rejected)
typedef float  vf4 __attribute__((ext_vector_type(4)));
typedef int    vi4 __attribute__((ext_vector_type(4)));

struct Ws {
  double moments[NB][5];                 // n, sum_p, sum_g, sum_pp, sum_pg (memset-zeroed)
  double loss_sum;                       // fused k_fin epilogue accumulator (memset-zeroed)
  unsigned long long done;               // fused k_fin done-counter (memset-zeroed)
  unsigned long long hist64[NB][NBINS];  // zeroed by k_mom threads (next-launch consumer)
};

__device__ __forceinline__ double wave_sum_d(double v) {
#pragma unroll
  for (int o = 32; o > 0; o >>= 1) v += __shfl_down(v, o, 64);
  return v;
}

__device__ __forceinline__ double block_sum_d(double v, double* red4) {
  v = wave_sum_d(v);
  const int lane = threadIdx.x & 63, w = threadIdx.x >> 6;
  if (lane == 0) red4[w] = v;
  __syncthreads();
  return red4[0] + red4[1] + red4[2] + red4[3];
}

__device__ __forceinline__ int k_from_n(double n) {
  return (int)floorf(0.8f * (float)n);   // matches jnp.floor((1-0.2)*n) in f32
}

__device__ __forceinline__ void coef_from_moments(const Ws* ws, int b, float* a_out, float* be_out) {
  const double n = ws->moments[b][0];
  const double ns = n > 1.0 ? n : 1.0;
  const double md = ws->moments[b][1] / ns;
  const double mz = ws->moments[b][2] / ns;
  const double var = ws->moments[b][3] / ns - md * md;
  const double cov = ws->moments[b][4] / ns - md * mz;
  const double a = cov / (var + 1e-6);
  *a_out = (float)a;
  *be_out = (float)(mz - a * md);
}

// exact sum of all residuals in `bin` given its packed (cnt, sum_low19)
__device__ __forceinline__ double bin_sum(int bin, unsigned long long h) {
  const double cnt = (double)(h >> 40);
  const double slow = (double)(h & SLOWMASK);
  const int e = bin >> 4, t4 = bin & 15;
  if (e == 0)  // subnormal: r = mant23 * 2^-149
    return ldexp(cnt * (double)(t4 << 19) + slow, -149);
  // r = 2^(e-127) * (1 + mant23*2^-23), mant23 = (t4<<19) + low19
  return ldexp(cnt * (1.0 + (double)t4 * 0.0625) + slow * (1.0 / 8388608.0), e - 127);
}

// ---------------- K1: moments + mask bitmap + zero hist region ----------------
template <bool BM>
__global__ __launch_bounds__(NT, 8) void k_mom(
    const float* __restrict__ pred, const float* __restrict__ gt,
    const int* __restrict__ mask, Ws* __restrict__ ws,
    unsigned long long* __restrict__ bm) {
  const int b = blockIdx.y;
  const size_t base = (size_t)b * NPIX + (size_t)blockIdx.x * K1CHUNK;
  const vf4* p4 = (const vf4*)(pred + base);
  const vf4* g4 = (const vf4*)(gt + base);
  const vi4* m4 = (const vi4*)(mask + base);
  __shared__ unsigned char nib[K1GROUPS];   // 2 KB: 4-px mask nibble per group
  __shared__ double red[4][5];
  float n = 0.f, sp = 0.f, sg = 0.f, spp = 0.f, spg = 0.f;
  for (int i = threadIdx.x; i < K1HALF4; i += NT) {
    // read-exactly-once streams: non-temporal -> no L2/L3 allocation, no
    // eviction of harness-restored warm lines. Round-1 A/B: plain loads were
    // 1.7x slower at identical FETCH_SIZE (L2-allocate path pure overhead).
    vf4 pa = __builtin_nontemporal_load(&p4[i]);
    vf4 pb = __builtin_nontemporal_load(&p4[i + K1HALF4]);
    vf4 ga = __builtin_nontemporal_load(&g4[i]);
    vf4 gb = __builtin_nontemporal_load(&g4[i + K1HALF4]);
    vi4 ma = __builtin_nontemporal_load(&m4[i]);
    vi4 mb = __builtin_nontemporal_load(&m4[i + K1HALF4]);
    const float pe[8] = {pa.x, pa.y, pa.z, pa.w, pb.x, pb.y, pb.z, pb.w};
    const float ge[8] = {ga.x, ga.y, ga.z, ga.w, gb.x, gb.y, gb.z, gb.w};
    const int   me[8] = {ma.x, ma.y, ma.z, ma.w, mb.x, mb.y, mb.z, mb.w};
#pragma unroll
    for (int j = 0; j < 8; j++) {
      const float mf = me[j] ? 1.f : 0.f;
      const float pm = pe[j] * mf;
      const float gm = ge[j] * mf;
      n += mf; sp += pm; sg += gm;
      spp = fmaf(pe[j], pm, spp);
      spg = fmaf(pe[j], gm, spg);
    }
    if (BM) {
      nib[i] = (unsigned char)((me[0] ? 1 : 0) | (me[1] ? 2 : 0) |
                               (me[2] ? 4 : 0) | (me[3] ? 8 : 0));
      nib[i + K1HALF4] = (unsigned char)((me[4] ? 1 : 0) | (me[5] ? 2 : 0) |
                                         (me[6] ? 4 : 0) | (me[7] ? 8 : 0));
    }
  }
  if (BM) {
    __syncthreads();
    if (threadIdx.x < K1WORDS) {   // assemble 16 nibbles -> one u64 bitmap word
      unsigned long long w = 0;
#pragma unroll
      for (int j = 0; j < 16; j++)
        w |= (unsigned long long)nib[threadIdx.x * 16 + j] << (4 * j);
      bm[base / 64 + threadIdx.x] = w;
    }
    // no second sync needed: nib is never touched again; epilogue uses red[][]
  }
  // merged epilogue: 5 wave reductions -> one LDS pass -> ONE sync -> 5
  // parallel atomics (round-3 win: k_mom 43.2 -> <40 us)
  double v[5] = {(double)n, (double)sp, (double)sg, (double)spp, (double)spg};
#pragma unroll
  for (int q = 0; q < 5; q++) v[q] = wave_sum_d(v[q]);
  const int lane = (int)threadIdx.x & 63, w = (int)threadIdx.x >> 6;
  if (lane == 0) {
#pragma unroll
    for (int q = 0; q < 5; q++) red[w][q] = v[q];
  }
  __syncthreads();
  if (threadIdx.x < 5) {
    const int q = (int)threadIdx.x;
    atomicAdd(&ws->moments[b][q], red[0][q] + red[1][q] + red[2][q] + red[3][q]);
  }
  // zero hist64 for k_hist (consumed next launch): one u64 per early thread
  const int flat = (b * K1CHUNKS + (int)blockIdx.x) * NT + (int)threadIdx.x;
  if (flat < NB * NBINS) ((unsigned long long*)ws->hist64)[flat] = 0ull;
}

// ---------------- K2: 4096-bin packed (cnt,sum_low19) histogram, f32 inputs ----------------
// Round-4 lesson: do NOT add post-flush __syncthreads/__threadfence here — the
// end-of-kernel implicit drain is free, explicit drain cost +28 us/dispatch.
// Round-5 win (+1.4 us): 2-deep p/g software pipeline — iteration j+1's
// non-temporal loads issue before iteration j's LDS-atomic cluster. Fits the
// 128-VGPR budget of __launch_bounds__(NT,4) (52 VGPRs). Round-6 lesson: going
// deeper is only safe while VGPR_Count stays well under 128.
template <bool BM>
__global__ __launch_bounds__(NT, 4) void k_hist(
    const float* __restrict__ pred, const float* __restrict__ gt,
    const int* __restrict__ mask, const unsigned long long* __restrict__ bm,
    Ws* __restrict__ ws) {
  __shared__ unsigned long long h64[NBINS];   // 32 KB
  __shared__ unsigned long long smask[K2WORDS];
  for (int i = threadIdx.x; i < NBINS; i += NT) h64[i] = 0ull;
  const int b = blockIdx.y;
  const int tid = (int)threadIdx.x;
  const size_t base = (size_t)b * NPIX + (size_t)blockIdx.x * K2CHUNK;
  if (BM) {
    if (tid < K2WORDS) smask[tid] = bm[base / 64 + tid];
  }
  float a, be;
  coef_from_moments(ws, b, &a, &be);
  __syncthreads();
  const vf4* p4 = (const vf4*)(pred + base);
  const vf4* g4 = (const vf4*)(gt + base);
  const vi4* m4 = (const vi4*)(mask + base);
  vf4 p = __builtin_nontemporal_load(&p4[tid]);
  vf4 g = __builtin_nontemporal_load(&g4[tid]);
  vi4 m;
  if (!BM) m = __builtin_nontemporal_load(&m4[tid]);
  for (int j = 0; j < K2IT; j++) {
    const int i = j * NT + tid;
    vf4 pn, gn;
    vi4 mn;
    if (j + 1 < K2IT) {   // prefetch next iteration before consuming current
      pn = __builtin_nontemporal_load(&p4[i + NT]);
      gn = __builtin_nontemporal_load(&g4[i + NT]);
      if (!BM) mn = __builtin_nontemporal_load(&m4[i + NT]);
    }
    const float pe[4] = {p.x, p.y, p.z, p.w};
    const float ge[4] = {g.x, g.y, g.z, g.w};
    int me[4];
    if (BM) {
      const unsigned int nb4 =
          (unsigned int)(smask[i >> 4] >> ((i & 15) * 4)) & 0xFu;
      me[0] = nb4 & 1; me[1] = nb4 & 2; me[2] = nb4 & 4; me[3] = nb4 & 8;
    } else {
      me[0] = m.x; me[1] = m.y; me[2] = m.z; me[3] = m.w;
    }
#pragma unroll
    for (int l = 0; l < 4; l++) {
      if (!me[l]) continue;
      const float r = fabsf(fmaf(a, pe[l], be) - ge[l]);
      const uint32_t t = __float_as_uint(r);
      atomicAdd(&h64[t >> 19], CNT1 | (unsigned long long)(t & 0x7FFFFu));
    }
    p = pn; g = gn;
    if (!BM) m = mn;
  }
  __syncthreads();
  // flush nonzero bins; consumed by k_fin in the NEXT launch (no fences needed);
  // waves retire with flush atomics in flight (implicit end-of-kernel drain).
  for (int i = tid; i < NBINS; i += NT) {
    const unsigned long long v = h64[i];
    if (v) atomicAdd(&ws->hist64[b][i], v);
  }
}

// ---------------- K3: per-sample trimmed mean + fused cross-sample average ----------------
__global__ __launch_bounds__(NT) void k_fin(Ws* __restrict__ ws, float* __restrict__ out) {
  const int b = (int)blockIdx.x;
  const int tid = (int)threadIdx.x;
  __shared__ int pc[NT];
  __shared__ int shX, shCum;
  __shared__ double red4[4];
  const unsigned long long* H = ws->hist64[b];
  unsigned long long h[16];
  int lc = 0;
#pragma unroll
  for (int j = 0; j < 16; j++) { h[j] = H[tid * 16 + j]; lc += (int)(h[j] >> 40); }
  pc[tid] = lc;
  if (tid == 0) { shX = NBINS; shCum = 0; }
  __syncthreads();
  int pre = 0;
  for (int t = 0; t < tid; t++) pre += pc[t];   // LDS broadcast reads
  const int k = k_from_n(ws->moments[b][0]);
  if (k > 0 && pre < k && pre + lc >= k) {      // exactly one thread
    int cum = pre;
#pragma unroll
    for (int j = 0; j < 16; j++) {
      const int c = (int)(h[j] >> 40);
      if (cum + c >= k) { shX = tid * 16 + j; shCum = cum; break; }
      cum += c;
    }
  }
  __syncthreads();
  const int X = shX;
  double below = 0.0;
#pragma unroll
  for (int j = 0; j < 16; j++) {
    const int idx = tid * 16 + j;
    if (idx < X) below += bin_sum(idx, h[j]);
  }
  const double tot = block_sum_d(below, red4);
  if (tid == 0) {
    double loss = 0.0;
    if (k > 0 && X < NBINS) {
      const unsigned long long hX = H[X];
      const double cX = (double)(hX >> 40);
      // crossing-bin partial at the bin's exact mean (bin rel. width 2^-4)
      const double partial = (double)(k - shCum) * (bin_sum(X, hX) / cX);
      loss = (tot + partial) / (double)k;
    }
    // fused k_out: device-scope accumulate; last block writes the mean.
    atomicAdd(&ws->loss_sum, loss);
    __threadfence();
    const unsigned long long old = atomicAdd(&ws->done, 1ull);
    if (old == (unsigned long long)(NB - 1)) {
      __threadfence();
      const double sum = atomicAdd(&ws->loss_sum, 0.0);  // coherent read at L2
      out[0] = (float)(sum / (double)NB);
    }
  }
}

extern "C" void kernel_launch(void* const* d_in, const int* in_sizes, int n_in,
                              void* d_out, int out_size, void* d_ws, size_t ws_size,
                              hipStream_t stream) {
  const float* pred = (const float*)d_in[0];
  const float* gt   = (const float*)d_in[1];
  const int*   mask = (const int*)d_in[2];
  float* out = (float*)d_out;
  Ws* ws = (Ws*)d_ws;

  const size_t boff = (sizeof(Ws) + 255) & ~(size_t)255;
  const size_t bbytes = (size_t)NB * NPIX / 8;                  // 2 MB mask bitmap
  const bool bm_ok = ws_size >= boff + bbytes;                  // environment-constant
  unsigned long long* bm = (unsigned long long*)((char*)d_ws + boff);

  // zero moments + loss_sum + done; hist64 is zeroed by k_mom's threads
  (void)hipMemsetAsync(d_ws, 0, sizeof(double) * NB * 5 + 16, stream);

  dim3 g1(K1CHUNKS, NB);
  dim3 g2(K2CHUNKS, NB);
  if (bm_ok) {
    k_mom<true><<<g1, NT, 0, stream>>>(pred, gt, mask, ws, bm);
    k_hist<true><<<g2, NT, 0, stream>>>(pred, gt, mask, bm, ws);
  } else {
    k_mom<false><<<g1, NT, 0, stream>>>(pred, gt, mask, ws, nullptr);
    k_hist<false><<<g2, NT, 0, stream>>>(pred, gt, mask, nullptr, ws);
  }
  k_fin<<<NB, NT, 0, stream>>>(ws, out);
}